// Round 1
// baseline (81.993 us; speedup 1.0000x reference)
//
#include <hip/hip_runtime.h>

// K_attention_MH: per-token Gaussian head-mixing.
// x: (B,T,H,hd) fp32, hd=64, H=16, C=1024. Per token:
//   K[h][g] = exp(-|x_h - x_g|^2 * sigma);  y = x + K @ x
// Memory-bound: 32 MB total traffic -> ~5 us floor.

#define NH 16
#define HD 64
#define CC 1024
// LDS layout: xs[d*17 + h]  (stride-17 transposed -> conflict-free for both
// the pairwise-distance reads (lanes vary h) and PV reads (lanes vary d)).

__global__ __launch_bounds__(256) void K_attention_MH_kernel(
    const float* __restrict__ x,
    const float* __restrict__ r_sigma,
    float* __restrict__ y) {
  __shared__ float xs[HD * 17];      // 64*17*4 = 4352 B
  __shared__ float Ks[NH * NH];      // 1 KB

  const int tok = blockIdx.x;
  const int tid = threadIdx.x;
  const float* xp = x + (size_t)tok * CC;
  float* yp = y + (size_t)tok * CC;
  const float sigma = r_sigma[0];

  // ---- load: 256 threads x float4 = 1024 floats, transpose into LDS ----
  const float4 v = reinterpret_cast<const float4*>(xp)[tid];
  const int base = tid * 4;
  const int h = base >> 6;   // head index, constant across the 4 elems
  const int d0 = base & 63;  // dim index of elem 0
  xs[(d0 + 0) * 17 + h] = v.x;
  xs[(d0 + 1) * 17 + h] = v.y;
  xs[(d0 + 2) * 17 + h] = v.z;
  xs[(d0 + 3) * 17 + h] = v.w;
  __syncthreads();

  // ---- pairwise squared distance + Gaussian kernel: thread <-> (hh,gg) ----
  {
    const int hh = tid >> 4;
    const int gg = tid & 15;
    float acc = 0.0f;
#pragma unroll
    for (int d = 0; d < HD; ++d) {
      const float a = xs[d * 17 + hh];
      const float b = xs[d * 17 + gg];
      const float diff = a - b;
      acc = fmaf(diff, diff, acc);
    }
    Ks[hh * 16 + gg] = __expf(-acc * sigma);
  }
  __syncthreads();

  // ---- y = x + K @ x : each thread computes its own 4 loaded elems ----
  float s0 = 0.0f, s1 = 0.0f, s2 = 0.0f, s3 = 0.0f;
#pragma unroll
  for (int g = 0; g < NH; ++g) {
    const float k = Ks[h * 16 + g];  // broadcast across wave
    s0 = fmaf(k, xs[(d0 + 0) * 17 + g], s0);
    s1 = fmaf(k, xs[(d0 + 1) * 17 + g], s1);
    s2 = fmaf(k, xs[(d0 + 2) * 17 + g], s2);
    s3 = fmaf(k, xs[(d0 + 3) * 17 + g], s3);
  }
  float4 o;
  o.x = v.x + s0;
  o.y = v.y + s1;
  o.z = v.z + s2;
  o.w = v.w + s3;
  reinterpret_cast<float4*>(yp)[tid] = o;
}

extern "C" void kernel_launch(void* const* d_in, const int* in_sizes, int n_in,
                              void* d_out, int out_size, void* d_ws, size_t ws_size,
                              hipStream_t stream) {
  const float* x = (const float*)d_in[0];
  const float* r_sigma = (const float*)d_in[1];
  float* out = (float*)d_out;
  const int ntok = in_sizes[0] / CC;  // B*T = 4096
  K_attention_MH_kernel<<<ntok, 256, 0, stream>>>(x, r_sigma, out);
}

// Round 2
// 69.365 us; speedup vs baseline: 1.1820x; 1.1820x over previous
//
#include <hip/hip_runtime.h>

// K_attention_MH: per-token Gaussian head-mixing, MFMA version.
//   G = X X^T (16x16x64)  via 2x mfma_f32_16x16x32_f16  (A-frag == B-frag)
//   dist2(h,g) = G_hh + G_gg - 2 G_hg ;  K = exp(-dist2*sigma)  (K symmetric)
//   Y = X + K @ X          via 4x mfma_f32_16x16x16f16  (K C-frag == A-frag, by symmetry)
// One wave per token; no block-level barriers (within-wave DS is in-order).

#define NH 16
#define HD 64
#define CC 1024
#define LDSROW 68  // floats; pad 4 keeps 16B alignment and spreads banks

typedef float  f32x4 __attribute__((ext_vector_type(4)));
typedef _Float16 f16x4 __attribute__((ext_vector_type(4)));
typedef _Float16 f16x8 __attribute__((ext_vector_type(8)));

__global__ __launch_bounds__(256) void K_attention_MH_kernel(
    const float* __restrict__ x,
    const float* __restrict__ r_sigma,
    float* __restrict__ y,
    int ntok) {
  __shared__ __align__(16) float xs[4][NH * LDSROW];  // 4 x 4.35 KB
  __shared__ __align__(16) float diag[4][NH];

  const int wid  = threadIdx.x >> 6;
  const int lane = threadIdx.x & 63;
  const int tok  = blockIdx.x * 4 + wid;
  if (tok >= ntok) return;

  const float* xp = x + (size_t)tok * CC;
  float*       yp = y + (size_t)tok * CC;
  float* xw = xs[wid];
  float* dw = diag[wid];
  const float sigma = r_sigma[0];

  const int q   = lane >> 4;   // 0..3
  const int col = lane & 15;   // 0..15

  // ---- stage: 4 contiguous float4 loads -> LDS rows (stride LDSROW) ----
#pragma unroll
  for (int i = 0; i < 4; ++i) {
    const float4 v = reinterpret_cast<const float4*>(xp)[lane + 64 * i];
    const int p = (lane + 64 * i) * 4;   // flat float index within token
    const int h = p >> 6, d = p & 63;
    *reinterpret_cast<float4*>(&xw[h * LDSROW + d]) = v;
  }
  __builtin_amdgcn_wave_barrier();  // keep compiler from hoisting reads above writes

  // ---- Gram: G = X X^T. Lane l holds X[col][8q+j] -> serves as A AND B frag ----
  f32x4 g = {0.f, 0.f, 0.f, 0.f};
#pragma unroll
  for (int kc = 0; kc < 2; ++kc) {
    const float4 a0 = *reinterpret_cast<const float4*>(&xw[col * LDSROW + 8 * q + 32 * kc]);
    const float4 a1 = *reinterpret_cast<const float4*>(&xw[col * LDSROW + 8 * q + 32 * kc + 4]);
    f16x8 af;
    af[0] = (_Float16)a0.x; af[1] = (_Float16)a0.y;
    af[2] = (_Float16)a0.z; af[3] = (_Float16)a0.w;
    af[4] = (_Float16)a1.x; af[5] = (_Float16)a1.y;
    af[6] = (_Float16)a1.z; af[7] = (_Float16)a1.w;
    g = __builtin_amdgcn_mfma_f32_16x16x32_f16(af, af, g, 0, 0, 0);
  }
  // g[r] = G[4q+r][col]

  // ---- diagonal extract (16 lanes write) + broadcast via tiny LDS ----
  if ((col >> 2) == q) {
    const int rsel = col & 3;
    const float dv = (rsel == 0) ? g[0] : (rsel == 1) ? g[1] : (rsel == 2) ? g[2] : g[3];
    dw[col] = dv;
  }
  __builtin_amdgcn_wave_barrier();
  const float dgc = dw[col];                                    // G[col][col]
  const f32x4 dh  = *reinterpret_cast<const f32x4*>(&dw[4 * q]); // G[4q+r][4q+r]

  // ---- K values: kv[r] = K[4q+r][col]; by symmetry also A[m=col][k=4q+r] ----
  f16x4 ka;
  f32x4 kv;
#pragma unroll
  for (int r = 0; r < 4; ++r) {
    const float d2 = dh[r] + dgc - 2.0f * g[r];
    const float kvr = __expf(-sigma * d2);
    kv[r] = kvr;
    ka[r] = (_Float16)kvr;
  }
  (void)kv;

  // ---- PV + residual + store, one 16-wide d-chunk per MFMA ----
#pragma unroll
  for (int c = 0; c < 4; ++c) {
    float xb[4];
    f16x4 bfr;
#pragma unroll
    for (int j = 0; j < 4; ++j) {
      xb[j]  = xw[(4 * q + j) * LDSROW + 16 * c + col];  // X[g=4q+j][d=16c+col]
      bfr[j] = (_Float16)xb[j];
    }
    f32x4 acc = {0.f, 0.f, 0.f, 0.f};
    acc = __builtin_amdgcn_mfma_f32_16x16x16f16(ka, bfr, acc, 0, 0, 0);
#pragma unroll
    for (int r = 0; r < 4; ++r) {
      // D[4q+r][16c+col] = (K@X)[h][d]; residual x is the j==r B-frag value
      yp[(4 * q + r) * HD + 16 * c + col] = xb[r] + acc[r];
    }
  }
}

extern "C" void kernel_launch(void* const* d_in, const int* in_sizes, int n_in,
                              void* d_out, int out_size, void* d_ws, size_t ws_size,
                              hipStream_t stream) {
  const float* x = (const float*)d_in[0];
  const float* r_sigma = (const float*)d_in[1];
  float* out = (float*)d_out;
  const int ntok = in_sizes[0] / CC;           // B*T = 4096
  const int blocks = (ntok + 3) / 4;           // 4 tokens (waves) per block
  K_attention_MH_kernel<<<blocks, 256, 0, stream>>>(x, r_sigma, out, ntok);
}